// Round 2
// 337.176 us; speedup vs baseline: 1.0734x; 1.0734x over previous
//
#include <hip/hip_runtime.h>

typedef unsigned short u16;
typedef unsigned int   u32;
typedef short bf16x8 __attribute__((ext_vector_type(8)));
typedef float f32x4  __attribute__((ext_vector_type(4)));

#define B_   8
#define C_   128
#define H_   128
#define W_   128
#define NH   4
#define D_   32
#define HW_  16384
#define SCALE 0.17677669529663687f
#define SCL2E 0.2550437602866803f   // SCALE * log2(e)

__device__ __forceinline__ float bf2f_u(u16 u) { union { u32 i; float f; } x; x.i = ((u32)u) << 16; return x.f; }
__device__ __forceinline__ float bflo(u32 u)   { union { u32 i; float f; } x; x.i = u << 16; return x.f; }
__device__ __forceinline__ float bfhi(u32 u)   { union { u32 i; float f; } x; x.i = u & 0xffff0000u; return x.f; }
__device__ __forceinline__ u16   f2bf(float f) {
  union { float f; u32 i; } x; x.f = f;
  u32 i = x.i;
  return (u16)((i + 0x7fffu + ((i >> 16) & 1u)) >> 16);
}
__device__ __forceinline__ u32 pk2(float a, float b) {
  return (u32)f2bf(a) | ((u32)f2bf(b) << 16);
}
__device__ __forceinline__ u32 cvtpk(float a, float b) {
  u32 r;
  asm("v_cvt_pk_bf16_f32 %0, %1, %2" : "=v"(r) : "v"(a), "v"(b));
  return r;
}
__device__ __forceinline__ bf16x8 ld_frag_g(const u16* p) {
  union { uint4 u; bf16x8 f; } c; c.u = *(const uint4*)p; return c.f;
}

// ---------------------------------------------------------------------------
// k_wcvt2: convert both weight tensors f32 -> bf16 in one launch.
// ---------------------------------------------------------------------------
__global__ __launch_bounds__(256) void k_wcvt2(const float* __restrict__ wq,
                                               const float* __restrict__ wp,
                                               u16* __restrict__ dq,
                                               u16* __restrict__ dp) {
  int i = blockIdx.x * 256 + threadIdx.x;
  const float* src; u16* dst; int j;
  if (i < 12288) { src = wq; dst = dq; j = i; }
  else           { src = wp; dst = dp; j = i - 12288; }
  float4 v = ((const float4*)src)[j];
  uint2 st; st.x = pk2(v.x, v.y); st.y = pk2(v.z, v.w);
  *(uint2*)(dst + (size_t)j * 4) = st;
}

// ---------------------------------------------------------------------------
// k_qkv: fused transpose + MFMA GEMM (unchanged).
// ---------------------------------------------------------------------------
__global__ __launch_bounds__(256) void k_qkv(const float* __restrict__ x,
                                             const u16* __restrict__ wqb,
                                             u16* __restrict__ qkvb) {
  __shared__ u32 tile[128 * 65];
  const int tid = threadIdx.x, w = tid >> 6, lane = tid & 63;
  const int c16 = lane & 15, rg = lane >> 4;
  const int b = blockIdx.z;
  const int P0 = blockIdx.x * 128;
  const float* sb = x + (size_t)b * C_ * HW_ + P0;

  #pragma unroll
  for (int ci = 0; ci < 4; ++ci) {
    int cp = 16 * w + 4 * ci + (lane >> 4);
    #pragma unroll
    for (int ph = 0; ph < 2; ++ph) {
      int p = 4 * (lane & 15) + 64 * ph;
      const float* r0 = sb + (size_t)(2 * cp) * HW_ + p;
      float4 a  = *(const float4*)r0;
      float4 bb = *(const float4*)(r0 + HW_);
      tile[(p + 0) * 65 + cp] = pk2(a.x, bb.x);
      tile[(p + 1) * 65 + cp] = pk2(a.y, bb.y);
      tile[(p + 2) * 65 + cp] = pk2(a.z, bb.z);
      tile[(p + 3) * 65 + cp] = pk2(a.w, bb.w);
    }
  }
  __syncthreads();

  const int pw = w * 32;
  bf16x8 bfr[2][4];
  #pragma unroll
  for (int nt = 0; nt < 2; ++nt)
    #pragma unroll
    for (int kk = 0; kk < 4; ++kk) {
      int p = pw + nt * 16 + c16;
      int cp0 = kk * 16 + rg * 4;
      union { u32 d[4]; bf16x8 f; } u;
      u.d[0] = tile[p * 65 + cp0];
      u.d[1] = tile[p * 65 + cp0 + 1];
      u.d[2] = tile[p * 65 + cp0 + 2];
      u.d[3] = tile[p * 65 + cp0 + 3];
      bfr[nt][kk] = u.f;
    }

  const int p0 = P0 + pw;
  const f32x4 zero = {0.f, 0.f, 0.f, 0.f};
  #pragma unroll 1
  for (int pass = 0; pass < 3; ++pass) {
    f32x4 acc[8][2];
    #pragma unroll
    for (int mt = 0; mt < 8; ++mt) { acc[mt][0] = zero; acc[mt][1] = zero; }

    #pragma unroll
    for (int kk = 0; kk < 4; ++kk) {
      #pragma unroll
      for (int mt = 0; mt < 8; ++mt) {
        bf16x8 af = ld_frag_g(wqb + (size_t)(pass * 128 + mt * 16 + c16) * 128 + kk * 32 + rg * 8);
        acc[mt][0] = __builtin_amdgcn_mfma_f32_16x16x32_bf16(af, bfr[0][kk], acc[mt][0], 0, 0, 0);
        acc[mt][1] = __builtin_amdgcn_mfma_f32_16x16x32_bf16(af, bfr[1][kk], acc[mt][1], 0, 0, 0);
      }
    }

    u16* ob = qkvb + (size_t)pass * ((size_t)B_ * NH * HW_ * D_);
    #pragma unroll
    for (int mt = 0; mt < 8; ++mt) {
      int head = mt >> 1, d0 = (mt & 1) * 16 + rg * 4;
      #pragma unroll
      for (int nt = 0; nt < 2; ++nt) {
        f32x4 oa = acc[mt][nt];
        uint2 st;
        st.x = pk2(oa[0], oa[1]);
        st.y = pk2(oa[2], oa[3]);
        int pix = p0 + nt * 16 + c16;
        *(uint2*)(ob + ((size_t)(b * NH + head) * HW_ + pix) * 32 + d0) = st;
      }
    }
  }
}

// ---------------------------------------------------------------------------
// k_proj: fused transpose + MFMA GEMM (unchanged).
// ---------------------------------------------------------------------------
__global__ __launch_bounds__(256) void k_proj(const u16* __restrict__ cv,
                                              const u16* __restrict__ wpb,
                                              float* __restrict__ out) {
  __shared__ u32 tile[128 * 65];
  const int tid = threadIdx.x, w = tid >> 6, lane = tid & 63;
  const int c16 = lane & 15, rg = lane >> 4;
  const int b = blockIdx.z;
  const int P0 = blockIdx.x * 128;
  const u16* sb = cv + (size_t)b * C_ * HW_ + P0;

  #pragma unroll
  for (int ci = 0; ci < 4; ++ci) {
    int cp = 16 * w + 4 * ci + (lane >> 4);
    #pragma unroll
    for (int ph = 0; ph < 2; ++ph) {
      int p = 4 * (lane & 15) + 64 * ph;
      const u16* r0 = sb + (size_t)(2 * cp) * HW_ + p;
      uint2 a  = *(const uint2*)r0;
      uint2 bb = *(const uint2*)(r0 + HW_);
      tile[(p + 0) * 65 + cp] = (a.x & 0xffffu) | (bb.x << 16);
      tile[(p + 1) * 65 + cp] = (a.x >> 16)     | (bb.x & 0xffff0000u);
      tile[(p + 2) * 65 + cp] = (a.y & 0xffffu) | (bb.y << 16);
      tile[(p + 3) * 65 + cp] = (a.y >> 16)     | (bb.y & 0xffff0000u);
    }
  }
  __syncthreads();

  const int pw = w * 32;
  bf16x8 bfr[2][4];
  #pragma unroll
  for (int nt = 0; nt < 2; ++nt)
    #pragma unroll
    for (int kk = 0; kk < 4; ++kk) {
      int p = pw + nt * 16 + c16;
      int cp0 = kk * 16 + rg * 4;
      union { u32 d[4]; bf16x8 f; } u;
      u.d[0] = tile[p * 65 + cp0];
      u.d[1] = tile[p * 65 + cp0 + 1];
      u.d[2] = tile[p * 65 + cp0 + 2];
      u.d[3] = tile[p * 65 + cp0 + 3];
      bfr[nt][kk] = u.f;
    }

  const int p0 = P0 + pw;
  const f32x4 zero = {0.f, 0.f, 0.f, 0.f};
  f32x4 acc[8][2];
  #pragma unroll
  for (int mt = 0; mt < 8; ++mt) { acc[mt][0] = zero; acc[mt][1] = zero; }

  #pragma unroll
  for (int kk = 0; kk < 4; ++kk) {
    #pragma unroll
    for (int mt = 0; mt < 8; ++mt) {
      bf16x8 af = ld_frag_g(wpb + (size_t)(mt * 16 + c16) * 128 + kk * 32 + rg * 8);
      acc[mt][0] = __builtin_amdgcn_mfma_f32_16x16x32_bf16(af, bfr[0][kk], acc[mt][0], 0, 0, 0);
      acc[mt][1] = __builtin_amdgcn_mfma_f32_16x16x32_bf16(af, bfr[1][kk], acc[mt][1], 0, 0, 0);
    }
  }

  float* ob = out + (size_t)b * C_ * HW_;
  #pragma unroll
  for (int mt = 0; mt < 8; ++mt) {
    #pragma unroll
    for (int nt = 0; nt < 2; ++nt) {
      f32x4 oa = acc[mt][nt];
      int pix = p0 + nt * 16 + c16;
      #pragma unroll
      for (int r = 0; r < 4; ++r) {
        int o = mt * 16 + rg * 4 + r;
        ob[(size_t)o * HW_ + pix] = oa[r];
      }
    }
  }
}

// ---------------------------------------------------------------------------
// k_attn_mfma R6: swapped QK^T (mfma(K,Q)) so P's z-dim is register-adjacent:
//  - bf16 pack via v_cvt_pk_bf16_f32, no cross-lane shuffles, full-wave b64
//    stores (was: 32 bpermute + 32 predicated b32 stores per mt).
//  - 1/l folded into decay running products (min(a,b)*c = min(ac,bc)):
//    P stored pre-normalized, no linv redistribution, no output muls.
//  - V^T staged in two 16-row phases -> LDS/wave halves (16*68 dw), block
//    LDS 34816 -> 17408: occupancy becomes VGPR-limited, not LDS-limited.
// P LDS layout identical to R5, so the PV path is unchanged.
// ---------------------------------------------------------------------------
__global__ __launch_bounds__(256) void k_attn_mfma(const u16* __restrict__ qb,
                                                   const u16* __restrict__ kb,
                                                   const u16* __restrict__ vb,
                                                   const float* __restrict__ gp,
                                                   u16* __restrict__ houtb,
                                                   u16* __restrict__ woutb) {
  __shared__ u32 lds[4][16 * 68];
  const int tid  = threadIdx.x;
  const int w    = tid >> 6;
  const int lane = tid & 63;
  const int head = blockIdx.y & 3;
  const int axis = blockIdx.y >> 2;
  const int b    = blockIdx.z;
  const int line = blockIdx.x * 4 + w;
  u32* vt = &lds[w][0];
  u32* pt = &lds[w][0];          // alias: vt dead after vf frags resident
  const size_t base = (size_t)(b * NH + head) * HW_ * D_;
  const float g = gp[0];
  const int c16 = lane & 15, rg = lane >> 4;
  const size_t pstride = axis ? (size_t)128 * D_ : (size_t)D_;
  const size_t lbase   = base + (size_t)line * (axis ? D_ : 128 * D_);

  // ---- load V pixel pair to regs (all 32 d of pixels 2*lane, 2*lane+1) ----
  u32 v0r[16], v1r[16];
  {
    const u16* v0p = vb + lbase + (size_t)(2 * lane) * pstride;
    const u16* v1p = v0p + pstride;
    #pragma unroll
    for (int t = 0; t < 4; ++t) {
      *(uint4*)&v0r[4 * t] = *(const uint4*)(v0p + 8 * t);
      *(uint4*)&v1r[4 * t] = *(const uint4*)(v1p + 8 * t);
    }
  }

  // ---- K B-frags from global (resident) ----
  bf16x8 kf[8];
  #pragma unroll
  for (int nt = 0; nt < 8; ++nt)
    kf[nt] = ld_frag_g(kb + lbase + (size_t)(nt * 16 + c16) * pstride + rg * 8);

  // ---- stage V^T two-phase (d 0..15 then 16..31) into 16x68; per-wave DS
  //      ops execute in order, so phase-B writes wait for phase-A reads. ----
  bf16x8 vf[2][4];
  #pragma unroll
  for (int ph = 0; ph < 2; ++ph) {
    #pragma unroll
    for (int dw = 0; dw < 8; ++dw) {
      u32 a = v0r[ph * 8 + dw], bq = v1r[ph * 8 + dw];
      u32 lo = (a & 0xffffu) | (bq << 16);
      u32 hi = (a >> 16) | (bq & 0xffff0000u);
      vt[(2 * dw) * 68 + lane]     = lo;
      vt[(2 * dw + 1) * 68 + lane] = hi;
    }
    #pragma unroll
    for (int t = 0; t < 4; ++t) {
      union { uint4 u; bf16x8 f; } c;
      c.u = *(const uint4*)(vt + c16 * 68 + t * 16 + rg * 4);
      vf[ph][t] = c.f;
    }
  }

  // ---- decay running products (swapped layout: z = nt*16+rg*4+r, j = c16) ----
  const float R1v  = __expf(-g),        Ri1v  = __expf(g);
  const float R12v = __expf(-12.f * g), Ri12v = __expf(12.f * g);
  const float R16v = __expf(-16.f * g), Ri16v = __expf(16.f * g);
  float t0 = (float)(rg * 4 - c16);
  float F  = __expf(-g * t0);
  float Fi = __expf(g * t0);

  u16* ob = axis ? woutb : houtb;
  const f32x4 zero = {0.f, 0.f, 0.f, 0.f};

  bf16x8 qf = ld_frag_g(qb + lbase + (size_t)c16 * pstride + rg * 8);

  #pragma unroll 1
  for (int mt = 0; mt < 8; ++mt) {
    int mtn = mt < 7 ? mt + 1 : 7;
    bf16x8 qf_n = ld_frag_g(qb + lbase + (size_t)(mtn * 16 + c16) * pstride + rg * 8);

    // S^T = K * Q^T : per lane row z = nt*16+rg*4+r, col j = c16
    f32x4 sa[8];
    #pragma unroll
    for (int nt = 0; nt < 8; ++nt)
      sa[nt] = __builtin_amdgcn_mfma_f32_16x16x32_bf16(kf[nt], qf, zero, 0, 0, 0);

    // exp (no max-subtract; scores provably small) + column sum over z
    float l = 0.f;
    #pragma unroll
    for (int nt = 0; nt < 8; ++nt)
      #pragma unroll
      for (int r = 0; r < 4; ++r) {
        float e = __builtin_amdgcn_exp2f(sa[nt][r] * SCL2E);
        l += e;
        sa[nt][r] = e;
      }
    l += __shfl_xor(l, 16);
    l += __shfl_xor(l, 32);
    float linv = __builtin_amdgcn_rcpf(l);

    // decay * 1/l fused; pack in-lane; full-wave b64 stores.
    // P LDS layout: row j = c16 (stride 68 dw), col dw = z/2.
    float f = F * linv, fi = Fi * linv;
    #pragma unroll
    for (int nt = 0; nt < 8; ++nt) {
      float pv0 = sa[nt][0] * fminf(f, fi); f *= R1v; fi *= Ri1v;
      float pv1 = sa[nt][1] * fminf(f, fi); f *= R1v; fi *= Ri1v;
      float pv2 = sa[nt][2] * fminf(f, fi); f *= R1v; fi *= Ri1v;
      float pv3 = sa[nt][3] * fminf(f, fi); f *= R1v; fi *= Ri1v;
      f *= R12v; fi *= Ri12v;
      uint2 st;
      st.x = cvtpk(pv0, pv1);
      st.y = cvtpk(pv2, pv3);
      *(uint2*)(pt + c16 * 68 + nt * 8 + rg * 2) = st;
    }
    F *= Ri16v; Fi *= R16v;

    // PV: A = P[j][z] from LDS (unchanged layout), B = V^T frags
    f32x4 oa0 = zero, oa1 = zero;
    #pragma unroll
    for (int t = 0; t < 4; ++t) {
      union { uint4 u; bf16x8 f; } af;
      af.u = *(const uint4*)(pt + c16 * 68 + t * 16 + rg * 4);
      oa0 = __builtin_amdgcn_mfma_f32_16x16x32_bf16(af.f, vf[0][t], oa0, 0, 0, 0);
      oa1 = __builtin_amdgcn_mfma_f32_16x16x32_bf16(af.f, vf[1][t], oa1, 0, 0, 0);
    }

    #pragma unroll
    for (int ntd = 0; ntd < 2; ++ntd) {
      f32x4 oa = ntd ? oa1 : oa0;
      int d = ntd * 16 + c16;
      size_t off = ((size_t)((b * C_ + head * D_ + d) * 128 + line)) * 128 + mt * 16 + rg * 4;
      uint2 st;
      st.x = cvtpk(oa[0], oa[1]);
      st.y = cvtpk(oa[2], oa[3]);
      *(uint2*)(ob + off) = st;
    }
    qf = qf_n;
  }
}

// ---------------------------------------------------------------------------
// k_conv: combine out_h + out_w^T, depthwise 3x3 SAME conv; bf16 out.
// ---------------------------------------------------------------------------
__global__ __launch_bounds__(256) void k_conv(const u16* __restrict__ hb,
                                              const u16* __restrict__ wb,
                                              const float* __restrict__ wdw,
                                              u16* __restrict__ convo) {
  __shared__ u16 t[128 * 136];
  const int tid = threadIdx.x;
  const int c = blockIdx.x, b = blockIdx.y;
  const size_t pb = (size_t)(b * C_ + c) * HW_;

  for (int i = tid; i < 2048; i += 256) {
    int e = i * 8; int r = e >> 7, col = e & 127;
    *(uint4*)&t[r * 136 + col] = *(const uint4*)(hb + pb + e);
  }
  __syncthreads();
  for (int i = tid; i < 4096; i += 256) {
    int e = i * 4; int wr = e >> 7, hc = e & 127;
    u32 u2[2]; *(uint2*)u2 = *(const uint2*)(wb + pb + e);
    float f0 = bflo(u2[0]), f1 = bfhi(u2[0]), f2v = bflo(u2[1]), f3 = bfhi(u2[1]);
    t[(hc + 0) * 136 + wr] = f2bf(bf2f_u(t[(hc + 0) * 136 + wr]) + f0);
    t[(hc + 1) * 136 + wr] = f2bf(bf2f_u(t[(hc + 1) * 136 + wr]) + f1);
    t[(hc + 2) * 136 + wr] = f2bf(bf2f_u(t[(hc + 2) * 136 + wr]) + f2v);
    t[(hc + 3) * 136 + wr] = f2bf(bf2f_u(t[(hc + 3) * 136 + wr]) + f3);
  }
  __syncthreads();

  float k9[9];
  #pragma unroll
  for (int i = 0; i < 9; ++i) k9[i] = wdw[c * 9 + i];

  for (int px = tid; px < HW_; px += 256) {
    int r = px >> 7, col = px & 127;
    float a = 0.f;
    #pragma unroll
    for (int di = 0; di < 3; ++di) {
      int rr = r + di - 1;
      if (rr < 0 || rr > 127) continue;
      #pragma unroll
      for (int dj = 0; dj < 3; ++dj) {
        int cc2 = col + dj - 1;
        if (cc2 < 0 || cc2 > 127) continue;
        a += k9[di * 3 + dj] * bf2f_u(t[rr * 136 + cc2]);
      }
    }
    convo[pb + px] = f2bf(a);
  }
}

// ---------------------------------------------------------------------------
extern "C" void kernel_launch(void* const* d_in, const int* in_sizes, int n_in,
                              void* d_out, int out_size, void* d_ws, size_t ws_size,
                              hipStream_t stream) {
  const float* x     = (const float*)d_in[0];
  const float* wqkv  = (const float*)d_in[1];
  const float* wproj = (const float*)d_in[2];
  const float* wdw   = (const float*)d_in[3];
  const float* gamma = (const float*)d_in[4];
  float* out = (float*)d_out;
  char* ws = (char*)d_ws;

  u16* q   = (u16*)(ws);                    // 32 MB [B,4,HW,32] bf16
  u16* k   = (u16*)(ws + 33554432ull);      // 32 MB
  u16* v   = (u16*)(ws + 67108864ull);      // 32 MB
  u16* hb  = (u16*)(ws + 100663296ull);     // 32 MB [B,C,H,W] bf16 (attn-H out)
  u16* wb  = (u16*)(ws + 134217728ull);     // 32 MB [B,C,W,H] bf16 (attn-W out)
  u16* cv  = (u16*)(ws + 167772160ull);     // 32 MB [B,C,HW] bf16 (conv out)
  u16* wqb = (u16*)(ws + 201326592ull);     // 96 KB bf16 qkv weights
  u16* wpb = (u16*)(ws + 201326592ull + 131072ull); // 32 KB bf16 proj weights

  k_wcvt2    <<<dim3(64),        256, 0, stream>>>(wqkv, wproj, wqb, wpb);
  k_qkv      <<<dim3(128, 1, 8), 256, 0, stream>>>(x, wqb, q);
  k_attn_mfma<<<dim3(32, 8, 8),  256, 0, stream>>>(q, k, v, gamma, hb, wb);
  k_conv     <<<dim3(128, 8),    256, 0, stream>>>(hb, wb, wdw, cv);
  k_proj     <<<dim3(128, 1, 8), 256, 0, stream>>>(cv, wpb, out);
}